// Round 7
// baseline (719.189 us; speedup 1.0000x reference)
//
#include <hip/hip_runtime.h>
#include <hip/hip_bf16.h>
#include <hip/hip_fp8.h>

#define NN   3072
#define NE   147456
#define NP   100000
#define HID  256
#define INCH 128
#define CATK 144
#define KPAD 160
#define FP8_S    1024.0f
#define FP8_IS   (1.0f / 1024.0f)
#define FP8_IS2  (1.0f / (1024.0f * 1024.0f))
#define MAXE 128

typedef __attribute__((ext_vector_type(4))) float    f32x4;
typedef __attribute__((ext_vector_type(8))) _Float16 f16x8;
typedef __attribute__((ext_vector_type(4))) _Float16 f16x4;
typedef __attribute__((ext_vector_type(8))) unsigned char u8x8;

__device__ __forceinline__ float fp8f(unsigned char b) {
  __hip_fp8_e4m3 t; t.__x = b; return (float)t;
}
__device__ __forceinline__ unsigned char f2fp8(float v) {
  __hip_fp8_e4m3 t(v); return t.__x;
}

// ---------------- async global->LDS (16B) ----------------
__device__ __forceinline__ void gload16(const void* g, void* l) {
  __builtin_amdgcn_global_load_lds((const __attribute__((address_space(1))) void*)g,
                                   (__attribute__((address_space(3))) void*)l, 16, 0, 0);
}

// ---------------- adjacency build + in-degree count ----------------
__global__ void edges_kernel(const int* __restrict__ ei, float* __restrict__ adj,
                             int* __restrict__ cnt) {
  int e = blockIdx.x * 256 + threadIdx.x;
  if (e < NE) {
    int s = ei[e], t = ei[NE + e];
    atomicAdd(&adj[(size_t)s * NN + t], 1.0f);
    atomicAdd(&cnt[t], 1);
  }
}

// row-normalize -> fp8 (scaled by FP8_S) + diag(rw) extract (unscaled)
__global__ void rownorm_kernel(const float* __restrict__ adj, unsigned char* __restrict__ rw,
                               float* __restrict__ diag1) {
  int row = blockIdx.x, tid = threadIdx.x;
  const float* ap = adj + (size_t)row * NN;
  float s = 0.f;
  for (int j = tid; j < NN; j += 256) s += ap[j];
  for (int d = 32; d; d >>= 1) s += __shfl_xor(s, d);
  __shared__ float w4[4];
  if ((tid & 63) == 0) w4[tid >> 6] = s;
  __syncthreads();
  float inv = 1.f / fmaxf(w4[0] + w4[1] + w4[2] + w4[3], 1.f);
  unsigned char* rp = rw + (size_t)row * NN;
  for (int j = tid; j < NN; j += 256) {
    float v = ap[j] * inv;
    rp[j] = f2fp8(v * FP8_S);
    if (j == row) diag1[row] = v;
  }
}

// ---------------- u8 64x64-tiled transpose, up to 2 pairs via blockIdx.z ----------------
__global__ void transpose2_u8_kernel(const unsigned char* __restrict__ in0,
                                     unsigned char* __restrict__ out0,
                                     const unsigned char* __restrict__ in1,
                                     unsigned char* __restrict__ out1) {
  const unsigned char* in = blockIdx.z ? in1 : in0;
  unsigned char* out = blockIdx.z ? out1 : out0;
  __shared__ unsigned char t[64][68];
  int bx = blockIdx.x, by = blockIdx.y, tid = threadIdx.x;
#pragma unroll
  for (int ii = 0; ii < 4; ii++) {
    int lin = ii * 256 + tid;
    int r = lin >> 4, c4 = (lin & 15) * 4;
    unsigned int v = *(const unsigned int*)(in + (size_t)(by * 64 + r) * NN + bx * 64 + c4);
    t[r][c4] = v & 255; t[r][c4 + 1] = (v >> 8) & 255;
    t[r][c4 + 2] = (v >> 16) & 255; t[r][c4 + 3] = v >> 24;
  }
  __syncthreads();
#pragma unroll
  for (int ii = 0; ii < 4; ii++) {
    int lin = ii * 256 + tid;
    int r = lin >> 4, c4 = (lin & 15) * 4;
    unsigned int v = (unsigned int)t[c4][r] | ((unsigned int)t[c4 + 1][r] << 8) |
                     ((unsigned int)t[c4 + 2][r] << 16) | ((unsigned int)t[c4 + 3][r] << 24);
    *(unsigned int*)(out + (size_t)(bx * 64 + r) * NN + by * 64 + c4) = v;
  }
}

// ---------------- fp8 MFMA GEMM: C = A * Bt^T (all scaled by FP8_S) ----------------
// 128x128 tile, BK=128 elems (128 B rows = exactly 32 banks), 4 waves,
// XOR-swizzled LDS (16B chunk ^= row&7 -> 2-way bank aliasing = free),
// XCD-chunked block swizzle. 24 K-iters (half the barrier drains of BK=64).
// R4 lesson: no epilogue grafts here. Epilogue rescales by 1/S -> fp8.
__global__ __launch_bounds__(256) void gemm_fp8_nt(const unsigned char* __restrict__ A,
                                                   const unsigned char* __restrict__ Bt,
                                                   unsigned char* __restrict__ C, int n) {
  __shared__ __align__(16) unsigned char As[128 * 128];
  __shared__ __align__(16) unsigned char Bs[128 * 128];
  const int nbx = n >> 7;
  const int nb = nbx * nbx;
  const int bid = blockIdx.x;
  const int cpx = nb >> 3;
  const int wg = (bid & 7) * cpx + (bid >> 3);
  const int by = wg / nbx, bx = wg % nbx;
  const int tid = threadIdx.x;
  const int lane = tid & 63, wave = tid >> 6;
  const int wr = wave >> 1, wc = wave & 1;
  const int rowA0 = by * 128, rowB0 = bx * 128;
  const int fr = lane & 15;
  const int kg = lane >> 4;       // k-group: byte offset kg*8 within K=32 slice
  const int sr = tid >> 3;        // stage row 0..31
  const int scd = tid & 7;        // stage 16B chunk 0..7
  f32x4 acc[4][4] = {};
  const int nkt = n >> 7;         // 24 for n=3072
  for (int kt = 0; kt < nkt; ++kt) {
    const int k0 = kt << 7;
#pragma unroll
    for (int s = 0; s < 4; s++) {
      const int row = sr + s * 32;
      const int cg = (scd ^ (row & 7)) << 4;   // inverse-swizzled global chunk
      gload16(A + (size_t)(rowA0 + row) * n + k0 + cg, As + row * 128 + scd * 16);
      gload16(Bt + (size_t)(rowB0 + row) * n + k0 + cg, Bs + row * 128 + scd * 16);
    }
    __syncthreads();
#pragma unroll
    for (int ks = 0; ks < 4; ks++) {
      const int kb = ks * 32 + kg * 8;   // byte offset 0..120 within 128-B K-tile
      const int kc = kb >> 4, kl = kb & 15;
      long af[4], bf[4];
#pragma unroll
      for (int i = 0; i < 4; i++) {
        const int Ra = wr * 64 + i * 16 + fr;
        const int Rb = wc * 64 + i * 16 + fr;
        af[i] = *(const long*)(As + Ra * 128 + ((kc ^ (Ra & 7)) << 4) + kl);
        bf[i] = *(const long*)(Bs + Rb * 128 + ((kc ^ (Rb & 7)) << 4) + kl);
      }
#pragma unroll
      for (int i = 0; i < 4; i++)
#pragma unroll
        for (int j = 0; j < 4; j++)
          acc[i][j] = __builtin_amdgcn_mfma_f32_16x16x32_fp8_fp8(af[i], bf[j], acc[i][j], 0, 0, 0);
    }
    __syncthreads();
  }
  const int crow0 = rowA0 + wr * 64, ccol0 = rowB0 + wc * 64;
#pragma unroll
  for (int i = 0; i < 4; i++)
#pragma unroll
    for (int j = 0; j < 4; j++)
#pragma unroll
      for (int r = 0; r < 4; r++) {
        int row = crow0 + i * 16 + (lane >> 4) * 4 + r;
        int col = ccol0 + j * 16 + (lane & 15);
        C[(size_t)row * n + col] = f2fp8(acc[i][j][r] * FP8_IS);
      }
}

// ---------------- all diagonals t=2..16 in one streaming pass (fp8 inputs) ----------
__global__ __launch_bounds__(256) void diag_all_kernel(
    const unsigned char* __restrict__ rw, const unsigned char* __restrict__ rw2,
    const unsigned char* __restrict__ rw4, const unsigned char* __restrict__ rw8,
    const unsigned char* __restrict__ rw12, const unsigned char* __restrict__ rwT,
    const unsigned char* __restrict__ rw2T, const unsigned char* __restrict__ rw3T,
    const unsigned char* __restrict__ rw4T, float* __restrict__ diags) {
  int row = blockIdx.x, tid = threadIdx.x;
  size_t base = (size_t)row * NN;
  const u8x8* pl1  = (const u8x8*)(rw + base);
  const u8x8* pl2  = (const u8x8*)(rw2 + base);
  const u8x8* pl4  = (const u8x8*)(rw4 + base);
  const u8x8* pl8  = (const u8x8*)(rw8 + base);
  const u8x8* pl12 = (const u8x8*)(rw12 + base);
  const u8x8* pr1  = (const u8x8*)(rwT + base);
  const u8x8* pr2  = (const u8x8*)(rw2T + base);
  const u8x8* pr3  = (const u8x8*)(rw3T + base);
  const u8x8* pr4  = (const u8x8*)(rw4T + base);
  float s[15];
#pragma unroll
  for (int k = 0; k < 15; k++) s[k] = 0.f;
  for (int j = tid; j < NN / 8; j += 256) {
    u8x8 L1 = pl1[j], L2 = pl2[j], L4 = pl4[j], L8 = pl8[j], L12 = pl12[j];
    u8x8 R1 = pr1[j], R2 = pr2[j], R3 = pr3[j], R4 = pr4[j];
#pragma unroll
    for (int r = 0; r < 8; r++) {
      float a1 = fp8f(L1[r]), a2 = fp8f(L2[r]), a4 = fp8f(L4[r]),
            a8 = fp8f(L8[r]), a12 = fp8f(L12[r]);
      float b1 = fp8f(R1[r]), b2 = fp8f(R2[r]), b3 = fp8f(R3[r]), b4 = fp8f(R4[r]);
      s[0]  += a1 * b1;  s[1]  += a2 * b1;  s[2]  += a2 * b2;
      s[3]  += a4 * b1;  s[4]  += a4 * b2;  s[5]  += a4 * b3;  s[6]  += a4 * b4;
      s[7]  += a8 * b1;  s[8]  += a8 * b2;  s[9]  += a8 * b3;  s[10] += a8 * b4;
      s[11] += a12 * b1; s[12] += a12 * b2; s[13] += a12 * b3; s[14] += a12 * b4;
    }
  }
  __shared__ float red[15][4];
  int wave = tid >> 6, lane = tid & 63;
#pragma unroll
  for (int k = 0; k < 15; k++) {
    float v = s[k];
    for (int d = 32; d; d >>= 1) v += __shfl_xor(v, d);
    if (lane == 0) red[k][wave] = v;
  }
  __syncthreads();
  if (tid < 15)
    diags[(size_t)(tid + 1) * NN + row] =
        (red[tid][0] + red[tid][1] + red[tid][2] + red[tid][3]) * FP8_IS2;
}

// ---------------- fp16 MFMA node GEMM: C[M][Nn] = A @ Bt^T + bias (+skip on hi cols) ----
__global__ __launch_bounds__(256) void gemm_f16_node(const _Float16* __restrict__ A,
                                                     const _Float16* __restrict__ Bt,
                                                     const float* __restrict__ bias,
                                                     const float* __restrict__ addhi,
                                                     float* __restrict__ C32,
                                                     _Float16* __restrict__ C16,
                                                     int M, int Nn, int K) {
  __shared__ _Float16 As[64 * 32];
  __shared__ _Float16 Bs[64 * 32];
  const int tid = threadIdx.x;
  const int lane = tid & 63, wave = tid >> 6;
  const int wr = wave >> 1, wc = wave & 1;
  const int m0 = blockIdx.y * 64, n0 = blockIdx.x * 64;
  const int fr = lane & 15, fk = (lane >> 4) * 8;
  const int gr = tid >> 2, gc = (tid & 3) * 8;
  f32x4 acc[2][2] = {};
  for (int k0 = 0; k0 < K; k0 += 32) {
    gload16(A + (size_t)(m0 + gr) * K + k0 + gc, As + tid * 8);
    gload16(Bt + (size_t)(n0 + gr) * K + k0 + gc, Bs + tid * 8);
    __syncthreads();
    f16x8 af[2], bf[2];
#pragma unroll
    for (int i = 0; i < 2; i++) {
      af[i] = *(const f16x8*)(As + (wr * 32 + i * 16 + fr) * 32 + fk);
      bf[i] = *(const f16x8*)(Bs + (wc * 32 + i * 16 + fr) * 32 + fk);
    }
#pragma unroll
    for (int i = 0; i < 2; i++)
#pragma unroll
      for (int j = 0; j < 2; j++)
        acc[i][j] = __builtin_amdgcn_mfma_f32_16x16x32_f16(af[i], bf[j], acc[i][j], 0, 0, 0);
    __syncthreads();
  }
  const int crow0 = m0 + wr * 32, ccol0 = n0 + wc * 32;
#pragma unroll
  for (int i = 0; i < 2; i++)
#pragma unroll
    for (int j = 0; j < 2; j++)
#pragma unroll
      for (int r = 0; r < 4; r++) {
        int row = crow0 + i * 16 + (lane >> 4) * 4 + r;
        int col = ccol0 + j * 16 + (lane & 15);
        float val = acc[i][j][r];
        if (bias) val += bias[col];
        if (addhi && col >= Nn - 256) val += addhi[(size_t)row * 256 + col - (Nn - 256)];
        if (C32) C32[(size_t)row * Nn + col] = val;
        if (C16) C16[(size_t)row * Nn + col] = (_Float16)val;
      }
}

// proj weight: [CATK][HID] f32 -> [HID][KPAD] f16
__global__ void wconv_proj_kernel(const float* __restrict__ W, _Float16* __restrict__ Wt) {
  int idx = blockIdx.x * 256 + threadIdx.x;
  if (idx >= HID * KPAD) return;
  int n = idx / KPAD, k = idx - n * KPAD;
  Wt[idx] = (k < CATK) ? (_Float16)W[(size_t)k * HID + n] : (_Float16)0.f;
}

// per-layer: Wq|Wk|Wv|Ws -> wt_cat [1024][256] f16; biases -> bcat[1024]
__global__ void wconv_cat_kernel(const float* __restrict__ Wq, const float* __restrict__ Wk,
                                 const float* __restrict__ Wv, const float* __restrict__ Wsk,
                                 const float* __restrict__ bq, const float* __restrict__ bk,
                                 const float* __restrict__ bv, const float* __restrict__ bsk,
                                 _Float16* __restrict__ wt, float* __restrict__ bcat) {
  int idx = blockIdx.x * 256 + threadIdx.x;
  if (idx < 1024) {
    int s = idx >> 8, j = idx & 255;
    bcat[idx] = (s == 0) ? bq[j] : (s == 1) ? bk[j] : (s == 2) ? bv[j] : bsk[j];
  }
  if (idx < 4 * HID * HID) {
    int nrow = idx >> 8, k = idx & 255;
    int s = nrow >> 8, nc = nrow & 255;
    const float* W = (s == 0) ? Wq : (s == 1) ? Wk : (s == 2) ? Wv : Wsk;
    wt[idx] = (_Float16)W[(size_t)k * HID + nc];
  }
}

// concat with inline PE
__global__ void concat16_kernel(const float* __restrict__ x, const float* __restrict__ diags,
                                const float* __restrict__ w, const float* __restrict__ bb,
                                _Float16* __restrict__ xc) {
  int idx = blockIdx.x * 256 + threadIdx.x;
  if (idx >= NN * KPAD) return;
  int i = idx / KPAD, c = idx - i * KPAD;
  float v;
  if (c < INCH) v = x[(size_t)i * INCH + c];
  else if (c < CATK) {
    int d = c - INCH;
    v = bb[d];
#pragma unroll
    for (int t = 0; t < 16; t++) v += diags[t * NN + i] * w[t * 16 + d];
  } else v = 0.f;
  xc[idx] = (_Float16)v;
}

// ---------------- CSR ----------------
__global__ void csr_scan_kernel(const int* __restrict__ cnt, int* __restrict__ off) {
  int lane = threadIdx.x;  // single wave
  const int per = NN / 64;
  int s = 0;
  for (int i = 0; i < per; i++) s += cnt[lane * per + i];
  int run = s;
  for (int d = 1; d < 64; d <<= 1) {
    int t = __shfl_up(run, d);
    if (lane >= d) run += t;
  }
  int acc = run - s;
  for (int i = 0; i < per; i++) {
    off[lane * per + i] = acc;
    acc += cnt[lane * per + i];
  }
  if (lane == 63) off[NN] = acc;
}

__global__ void csr_fill_kernel(const int* __restrict__ sidx, const int* __restrict__ tidx,
                                const int* __restrict__ off, int* __restrict__ cur,
                                int* __restrict__ csrc) {
  int e = blockIdx.x * 256 + threadIdx.x;
  if (e >= NE) return;
  int t = tidx[e];
  int pos = atomicAdd(&cur[t], 1);
  csrc[off[t] + pos] = sidx[e];
}

// ---------------- fused attention + LayerNorm + ReLU, two-phase ----------------
__global__ __launch_bounds__(256) void attn_ln_kernel(const int* __restrict__ off,
                                                      const int* __restrict__ csrc,
                                                      const _Float16* __restrict__ qkvz,
                                                      const float* __restrict__ g,
                                                      const float* __restrict__ b,
                                                      float* __restrict__ hb,
                                                      _Float16* __restrict__ h16) {
  int node = blockIdx.x, tid = threadIdx.x;
  int h = tid >> 6, lane = tid & 63;
  int beg = off[node], end = off[node + 1];
  __shared__ _Float16 qs[256];
  __shared__ int srcs[MAXE];
  __shared__ float ps[4][MAXE];
  qs[tid] = qkvz[(size_t)node * 1024 + tid];
  float m_run = -INFINITY, d_run = 0.f, acc = 0.f;
  for (int chunk = beg; chunk < end; chunk += MAXE) {
    int ne = min(end - chunk, MAXE);
    if (tid < ne) srcs[tid] = csrc[chunk + tid];
    __syncthreads();
    // scores
    for (int p = tid; p < ne * 4; p += 256) {
      int e = p >> 2, h2 = p & 3;
      const f16x8* krow = (const f16x8*)(qkvz + (size_t)srcs[e] * 1024 + 256 + h2 * 64);
      const f16x8* qrow = (const f16x8*)(qs + h2 * 64);
      float sc = 0.f;
#pragma unroll
      for (int d8 = 0; d8 < 8; d8++) {
        f16x8 kv = krow[d8], qv = qrow[d8];
#pragma unroll
        for (int r = 0; r < 8; r++) sc += (float)qv[r] * (float)kv[r];
      }
      ps[h2][e] = sc * 0.125f;
    }
    __syncthreads();
    // per-head max
    float mloc = -INFINITY;
    for (int e = lane; e < ne; e += 64) mloc = fmaxf(mloc, ps[h][e]);
    for (int d = 32; d; d >>= 1) mloc = fmaxf(mloc, __shfl_xor(mloc, d));
    float mnew = fmaxf(m_run, mloc);
    // exp in place + denom
    float dloc = 0.f;
    for (int e = lane; e < ne; e += 64) {
      float p = __expf(ps[h][e] - mnew);
      ps[h][e] = p;
      dloc += p;
    }
    for (int d = 32; d; d >>= 1) dloc += __shfl_xor(dloc, d);
    float scale = __expf(m_run - mnew);   // exp(-inf)=0 on first chunk
    d_run = d_run * scale + dloc;
    acc *= scale;
    // V accumulate (iterations independent -> memory ILP)
    for (int e = 0; e < ne; e++) {
      acc += ps[h][e] * (float)qkvz[(size_t)srcs[e] * 1024 + 512 + h * 64 + lane];
    }
    m_run = mnew;
    __syncthreads();
  }
  float agg = acc / fmaxf(d_run, 1e-16f);
  float z = (float)qkvz[(size_t)node * 1024 + 768 + tid] + agg;
  // LayerNorm over 256
  float s = z;
  for (int d = 32; d; d >>= 1) s += __shfl_xor(s, d);
  __shared__ float w4[4], w4b[4];
  if (lane == 0) w4[h] = s;
  __syncthreads();
  float mu = (w4[0] + w4[1] + w4[2] + w4[3]) * (1.f / HID);
  float dv = z - mu;
  float qv = dv * dv;
  for (int d = 32; d; d >>= 1) qv += __shfl_xor(qv, d);
  if (lane == 0) w4b[h] = qv;
  __syncthreads();
  float var = (w4b[0] + w4b[1] + w4b[2] + w4b[3]) * (1.f / HID);
  float y = dv * (1.f / sqrtf(var + 1e-5f)) * g[tid] + b[tid];
  y = fmaxf(y, 0.f);
  hb[(size_t)node * HID + tid] = y;
  h16[(size_t)node * HID + tid] = (_Float16)y;
}

// decode from fp16 h (halves L2 gather traffic; error << bf16 quantization floor)
__global__ void decode_kernel(const _Float16* __restrict__ h, const int* __restrict__ src,
                              const int* __restrict__ dst, float* __restrict__ out) {
  int wv = threadIdx.x >> 6, lane = threadIdx.x & 63;
  int p = blockIdx.x * 4 + wv;
  if (p >= NP) return;
  const f16x4* a = (const f16x4*)(h + (size_t)src[p] * HID);
  const f16x4* b = (const f16x4*)(h + (size_t)dst[p] * HID);
  f16x4 x = a[lane], y = b[lane];
  float s = (float)x[0] * (float)y[0] + (float)x[1] * (float)y[1] +
            (float)x[2] * (float)y[2] + (float)x[3] * (float)y[3];
  for (int d = 32; d; d >>= 1) s += __shfl_xor(s, d);
  if (lane == 0) out[p] = 1.f / (1.f + expf(-s));
}

// ---------------- host launch ----------------
extern "C" void kernel_launch(void* const* d_in, const int* in_sizes, int n_in,
                              void* d_out, int out_size, void* d_ws, size_t ws_size,
                              hipStream_t stream) {
  const float* x      = (const float*)d_in[0];
  const int*   ei     = (const int*)d_in[1];
  const int*   src    = (const int*)d_in[2];
  const int*   dst    = (const int*)d_in[3];
  const float* rwse_w = (const float*)d_in[4];
  const float* rwse_b = (const float*)d_in[5];
  const float* proj_w = (const float*)d_in[6];
  const float* proj_b = (const float*)d_in[7];
  const float* Wq     = (const float*)d_in[8];
  const float* bq     = (const float*)d_in[9];
  const float* Wk     = (const float*)d_in[10];
  const float* bk     = (const float*)d_in[11];
  const float* Wv     = (const float*)d_in[12];
  const float* bv     = (const float*)d_in[13];
  const float* Wsk    = (const float*)d_in[14];
  const float* bs     = (const float*)d_in[15];
  const float* ln_g   = (const float*)d_in[16];
  const float* ln_b   = (const float*)d_in[17];
  float* out = (float*)d_out;

  const size_t M8 = (size_t)NN * NN;    // 9,437,184 bytes per fp8 matrix
  char* base = (char*)d_ws;
  unsigned char* rw   = (unsigned char*)(base + 0 * M8);
  unsigned char* rwT  = (unsigned char*)(base + 1 * M8);
  unsigned char* rw2  = (unsigned char*)(base + 2 * M8);
  unsigned char* rw3  = (unsigned char*)(base + 3 * M8);
  unsigned char* rw4  = (unsigned char*)(base + 4 * M8);
  unsigned char* rw4T = (unsigned char*)(base + 5 * M8);
  unsigned char* rw8  = (unsigned char*)(base + 6 * M8);
  unsigned char* rw12 = (unsigned char*)(base + 7 * M8);
  unsigned char* rw2T = (unsigned char*)(base + 8 * M8);
  unsigned char* rw3T = (unsigned char*)(base + 9 * M8);
  float* adj = (float*)(base + 6 * M8);  // f32 [NN][NN] = 4 fp8 slots (6..9); dead before rw8 written
  char* sm = base + 10 * M8;
  float* diags = (float*)sm; sm += (size_t)16 * NN * 4;
  int* cnt = (int*)sm; sm += 12288;
  int* cur = (int*)sm; sm += 12288;
  int* off = (int*)sm; sm += 16384;
  int* csrc = (int*)sm; sm += (size_t)NE * 4;
  float* hbuf = (float*)sm; sm += (size_t)NN * HID * 4;
  _Float16* qkvz16 = (_Float16*)sm; sm += (size_t)NN * 1024 * 2;
  _Float16* h16  = (_Float16*)sm; sm += (size_t)NN * HID * 2;
  _Float16* xc16 = (_Float16*)sm; sm += (size_t)NN * KPAD * 2;
  _Float16* wt_proj = (_Float16*)sm; sm += (size_t)HID * KPAD * 2;
  _Float16* wt_cat[2]; float* bcat[2];
  for (int l = 0; l < 2; ++l) {
    wt_cat[l] = (_Float16*)sm; sm += (size_t)4 * HID * HID * 2;
    bcat[l]   = (float*)sm;    sm += 1024 * 4;
  }
  (void)in_sizes; (void)n_in; (void)out_size; (void)ws_size;

  const dim3 B256(256);
  const dim3 gT1(NN / 64, NN / 64, 1);
  const dim3 gT2(NN / 64, NN / 64, 2);
  const int  gG = (NN / 128) * (NN / 128);     // 576
  const dim3 gW(1024 / 64, NN / 64);
  const dim3 gS(HID / 64, NN / 64);

  // --- weight prep ---
  wconv_proj_kernel<<<(HID * KPAD + 255) / 256, B256, 0, stream>>>(proj_w, wt_proj);
  for (int l = 0; l < 2; ++l)
    wconv_cat_kernel<<<(4 * HID * HID + 255) / 256, B256, 0, stream>>>(
        Wq + (size_t)l * HID * HID, Wk + (size_t)l * HID * HID, Wv + (size_t)l * HID * HID,
        Wsk + (size_t)l * HID * HID, bq + l * HID, bk + l * HID, bv + l * HID, bs + l * HID,
        wt_cat[l], bcat[l]);

  // --- adjacency + in-degree + CSR ---
  hipMemsetAsync(adj, 0, (size_t)NN * NN * 4, stream);
  hipMemsetAsync(cnt, 0, 24576, stream);   // cnt + cur contiguous
  edges_kernel<<<(NE + 255) / 256, B256, 0, stream>>>(ei, adj, cnt);
  rownorm_kernel<<<NN, B256, 0, stream>>>(adj, rw, diags);
  csr_scan_kernel<<<1, 64, 0, stream>>>(cnt, off);
  csr_fill_kernel<<<(NE + 255) / 256, B256, 0, stream>>>(ei, ei + NE, off, cur, csrc);

  // --- RWSE power chain (fp8, uniformly scaled by FP8_S) ---
  transpose2_u8_kernel<<<gT1, B256, 0, stream>>>(rw, rwT, rw, rwT);
  gemm_fp8_nt<<<gG, B256, 0, stream>>>(rw, rwT, rw2, NN);    // rw2 = rw*rw
  gemm_fp8_nt<<<gG, B256, 0, stream>>>(rw2, rwT, rw3, NN);   // rw3 = rw2*rw
  gemm_fp8_nt<<<gG, B256, 0, stream>>>(rw3, rwT, rw4, NN);   // rw4 = rw3*rw
  transpose2_u8_kernel<<<gT1, B256, 0, stream>>>(rw4, rw4T, rw4, rw4T);
  gemm_fp8_nt<<<gG, B256, 0, stream>>>(rw4, rw4T, rw8, NN);  // rw8 = rw4*rw4
  gemm_fp8_nt<<<gG, B256, 0, stream>>>(rw8, rw4T, rw12, NN); // rw12 = rw8*rw4
  transpose2_u8_kernel<<<gT2, B256, 0, stream>>>(rw2, rw2T, rw3, rw3T);
  diag_all_kernel<<<NN, B256, 0, stream>>>(rw, rw2, rw4, rw8, rw12,
                                           rwT, rw2T, rw3T, rw4T, diags);

  // --- input projection (PE inline in concat) ---
  concat16_kernel<<<(NN * KPAD + 255) / 256, B256, 0, stream>>>(x, diags, rwse_w, rwse_b, xc16);
  gemm_f16_node<<<gS, B256, 0, stream>>>(xc16, wt_proj, proj_b, nullptr, hbuf, h16,
                                         NN, HID, KPAD);

  // --- transformer layers ---
  for (int l = 0; l < 2; ++l) {
    gemm_f16_node<<<gW, B256, 0, stream>>>(h16, wt_cat[l], bcat[l], hbuf, nullptr, qkvz16,
                                           NN, 1024, HID);
    attn_ln_kernel<<<NN, B256, 0, stream>>>(off, csrc, qkvz16, ln_g + l * HID, ln_b + l * HID,
                                            hbuf, h16);
  }

  decode_kernel<<<NP / 4, B256, 0, stream>>>(h16, src, dst, out);
}

// Round 8
// 520.249 us; speedup vs baseline: 1.3824x; 1.3824x over previous
//
#include <hip/hip_runtime.h>
#include <hip/hip_bf16.h>
#include <hip/hip_fp8.h>

#define NN   3072
#define NE   147456
#define NP   100000
#define HID  256
#define INCH 128
#define CATK 144
#define KPAD 160
#define FP8_S    1024.0f
#define FP8_IS   (1.0f / 1024.0f)
#define FP8_IS2  (1.0f / (1024.0f * 1024.0f))
#define MAXE 128

typedef __attribute__((ext_vector_type(4))) float    f32x4;
typedef __attribute__((ext_vector_type(8))) _Float16 f16x8;
typedef __attribute__((ext_vector_type(4))) _Float16 f16x4;
typedef __attribute__((ext_vector_type(8))) unsigned char u8x8;
typedef __attribute__((ext_vector_type(4))) int i32x4;
typedef __attribute__((ext_vector_type(8))) int i32x8;

__device__ __forceinline__ float fp8f(unsigned char b) {
  __hip_fp8_e4m3 t; t.__x = b; return (float)t;
}
__device__ __forceinline__ unsigned char f2fp8(float v) {
  __hip_fp8_e4m3 t(v); return t.__x;
}

// ---------------- async global->LDS (16B) ----------------
__device__ __forceinline__ void gload16(const void* g, void* l) {
  __builtin_amdgcn_global_load_lds((const __attribute__((address_space(1))) void*)g,
                                   (__attribute__((address_space(3))) void*)l, 16, 0, 0);
}

// ---------------- adjacency build + in-degree count ----------------
__global__ void edges_kernel(const int* __restrict__ ei, float* __restrict__ adj,
                             int* __restrict__ cnt) {
  int e = blockIdx.x * 256 + threadIdx.x;
  if (e < NE) {
    int s = ei[e], t = ei[NE + e];
    atomicAdd(&adj[(size_t)s * NN + t], 1.0f);
    atomicAdd(&cnt[t], 1);
  }
}

// row-normalize -> fp8 (scaled by FP8_S) + diag(rw) extract (unscaled)
__global__ void rownorm_kernel(const float* __restrict__ adj, unsigned char* __restrict__ rw,
                               float* __restrict__ diag1) {
  int row = blockIdx.x, tid = threadIdx.x;
  const float* ap = adj + (size_t)row * NN;
  float s = 0.f;
  for (int j = tid; j < NN; j += 256) s += ap[j];
  for (int d = 32; d; d >>= 1) s += __shfl_xor(s, d);
  __shared__ float w4[4];
  if ((tid & 63) == 0) w4[tid >> 6] = s;
  __syncthreads();
  float inv = 1.f / fmaxf(w4[0] + w4[1] + w4[2] + w4[3], 1.f);
  unsigned char* rp = rw + (size_t)row * NN;
  for (int j = tid; j < NN; j += 256) {
    float v = ap[j] * inv;
    rp[j] = f2fp8(v * FP8_S);
    if (j == row) diag1[row] = v;
  }
}

// ---------------- u8 64x64-tiled transpose, up to 2 pairs via blockIdx.z ----------------
__global__ void transpose2_u8_kernel(const unsigned char* __restrict__ in0,
                                     unsigned char* __restrict__ out0,
                                     const unsigned char* __restrict__ in1,
                                     unsigned char* __restrict__ out1) {
  const unsigned char* in = blockIdx.z ? in1 : in0;
  unsigned char* out = blockIdx.z ? out1 : out0;
  __shared__ unsigned char t[64][68];
  int bx = blockIdx.x, by = blockIdx.y, tid = threadIdx.x;
#pragma unroll
  for (int ii = 0; ii < 4; ii++) {
    int lin = ii * 256 + tid;
    int r = lin >> 4, c4 = (lin & 15) * 4;
    unsigned int v = *(const unsigned int*)(in + (size_t)(by * 64 + r) * NN + bx * 64 + c4);
    t[r][c4] = v & 255; t[r][c4 + 1] = (v >> 8) & 255;
    t[r][c4 + 2] = (v >> 16) & 255; t[r][c4 + 3] = v >> 24;
  }
  __syncthreads();
#pragma unroll
  for (int ii = 0; ii < 4; ii++) {
    int lin = ii * 256 + tid;
    int r = lin >> 4, c4 = (lin & 15) * 4;
    unsigned int v = (unsigned int)t[c4][r] | ((unsigned int)t[c4 + 1][r] << 8) |
                     ((unsigned int)t[c4 + 2][r] << 16) | ((unsigned int)t[c4 + 3][r] << 24);
    *(unsigned int*)(out + (size_t)(bx * 64 + r) * NN + by * 64 + c4) = v;
  }
}

// ---------------- MX-fp8 MFMA GEMM: C = A * Bt^T (all scaled by FP8_S) ----------------
// 128x128 tile, BK=128 (one K=128 mfma_scale per fragment pair), 4 waves,
// XOR-swizzled LDS (16B chunk ^= row&7), XCD-chunked block swizzle.
// mfma_scale_f32_16x16x128_f8f6f4 with E8M0 scales = 127 (1.0): 2x K-rate vs
// plain fp8 (guide ladder m148: 995->1628 TF on this same structure).
// R4 lesson: no epilogue grafts here. Epilogue rescales by 1/S -> fp8.
__global__ __launch_bounds__(256) void gemm_fp8_nt(const unsigned char* __restrict__ A,
                                                   const unsigned char* __restrict__ Bt,
                                                   unsigned char* __restrict__ C, int n) {
  __shared__ __align__(16) unsigned char As[128 * 128];
  __shared__ __align__(16) unsigned char Bs[128 * 128];
  const int nbx = n >> 7;
  const int nb = nbx * nbx;
  const int bid = blockIdx.x;
  const int cpx = nb >> 3;
  const int wg = (bid & 7) * cpx + (bid >> 3);
  const int by = wg / nbx, bx = wg % nbx;
  const int tid = threadIdx.x;
  const int lane = tid & 63, wave = tid >> 6;
  const int wr = wave >> 1, wc = wave & 1;
  const int rowA0 = by * 128, rowB0 = bx * 128;
  const int fr = lane & 15;
  const int kg = lane >> 4;       // k-group: 32-byte slice kg*32 within K=128
  const int sr = tid >> 3;        // stage row 0..31
  const int scd = tid & 7;        // stage 16B chunk 0..7
  f32x4 acc[4][4] = {};
  const int nkt = n >> 7;         // 24 for n=3072
  for (int kt = 0; kt < nkt; ++kt) {
    const int k0 = kt << 7;
#pragma unroll
    for (int s = 0; s < 4; s++) {
      const int row = sr + s * 32;
      const int cg = (scd ^ (row & 7)) << 4;   // inverse-swizzled global chunk
      gload16(A + (size_t)(rowA0 + row) * n + k0 + cg, As + row * 128 + scd * 16);
      gload16(Bt + (size_t)(rowB0 + row) * n + k0 + cg, Bs + row * 128 + scd * 16);
    }
    __syncthreads();
    i32x8 af[4], bf[4];
#pragma unroll
    for (int i = 0; i < 4; i++) {
      const int Ra = wr * 64 + i * 16 + fr;
      const int Rb = wc * 64 + i * 16 + fr;
      const int c0a = ((2 * kg) ^ (Ra & 7)) << 4, c1a = ((2 * kg + 1) ^ (Ra & 7)) << 4;
      const int c0b = ((2 * kg) ^ (Rb & 7)) << 4, c1b = ((2 * kg + 1) ^ (Rb & 7)) << 4;
      i32x4 alo = *(const i32x4*)(As + Ra * 128 + c0a);
      i32x4 ahi = *(const i32x4*)(As + Ra * 128 + c1a);
      i32x4 blo = *(const i32x4*)(Bs + Rb * 128 + c0b);
      i32x4 bhi = *(const i32x4*)(Bs + Rb * 128 + c1b);
      af[i] = (i32x8){alo[0], alo[1], alo[2], alo[3], ahi[0], ahi[1], ahi[2], ahi[3]};
      bf[i] = (i32x8){blo[0], blo[1], blo[2], blo[3], bhi[0], bhi[1], bhi[2], bhi[3]};
    }
#pragma unroll
    for (int i = 0; i < 4; i++)
#pragma unroll
      for (int j = 0; j < 4; j++)
        acc[i][j] = __builtin_amdgcn_mfma_scale_f32_16x16x128_f8f6f4(
            af[i], bf[j], acc[i][j], 0, 0, 0, 127, 0, 127);
    __syncthreads();
  }
  const int crow0 = rowA0 + wr * 64, ccol0 = rowB0 + wc * 64;
#pragma unroll
  for (int i = 0; i < 4; i++)
#pragma unroll
    for (int j = 0; j < 4; j++)
#pragma unroll
      for (int r = 0; r < 4; r++) {
        int row = crow0 + i * 16 + (lane >> 4) * 4 + r;
        int col = ccol0 + j * 16 + (lane & 15);
        C[(size_t)row * n + col] = f2fp8(acc[i][j][r] * FP8_IS);
      }
}

// ---------------- all diagonals t=2..16 in one streaming pass (fp8 inputs) ----------
__global__ __launch_bounds__(256) void diag_all_kernel(
    const unsigned char* __restrict__ rw, const unsigned char* __restrict__ rw2,
    const unsigned char* __restrict__ rw4, const unsigned char* __restrict__ rw8,
    const unsigned char* __restrict__ rw12, const unsigned char* __restrict__ rwT,
    const unsigned char* __restrict__ rw2T, const unsigned char* __restrict__ rw3T,
    const unsigned char* __restrict__ rw4T, float* __restrict__ diags) {
  int row = blockIdx.x, tid = threadIdx.x;
  size_t base = (size_t)row * NN;
  const u8x8* pl1  = (const u8x8*)(rw + base);
  const u8x8* pl2  = (const u8x8*)(rw2 + base);
  const u8x8* pl4  = (const u8x8*)(rw4 + base);
  const u8x8* pl8  = (const u8x8*)(rw8 + base);
  const u8x8* pl12 = (const u8x8*)(rw12 + base);
  const u8x8* pr1  = (const u8x8*)(rwT + base);
  const u8x8* pr2  = (const u8x8*)(rw2T + base);
  const u8x8* pr3  = (const u8x8*)(rw3T + base);
  const u8x8* pr4  = (const u8x8*)(rw4T + base);
  float s[15];
#pragma unroll
  for (int k = 0; k < 15; k++) s[k] = 0.f;
  for (int j = tid; j < NN / 8; j += 256) {
    u8x8 L1 = pl1[j], L2 = pl2[j], L4 = pl4[j], L8 = pl8[j], L12 = pl12[j];
    u8x8 R1 = pr1[j], R2 = pr2[j], R3 = pr3[j], R4 = pr4[j];
#pragma unroll
    for (int r = 0; r < 8; r++) {
      float a1 = fp8f(L1[r]), a2 = fp8f(L2[r]), a4 = fp8f(L4[r]),
            a8 = fp8f(L8[r]), a12 = fp8f(L12[r]);
      float b1 = fp8f(R1[r]), b2 = fp8f(R2[r]), b3 = fp8f(R3[r]), b4 = fp8f(R4[r]);
      s[0]  += a1 * b1;  s[1]  += a2 * b1;  s[2]  += a2 * b2;
      s[3]  += a4 * b1;  s[4]  += a4 * b2;  s[5]  += a4 * b3;  s[6]  += a4 * b4;
      s[7]  += a8 * b1;  s[8]  += a8 * b2;  s[9]  += a8 * b3;  s[10] += a8 * b4;
      s[11] += a12 * b1; s[12] += a12 * b2; s[13] += a12 * b3; s[14] += a12 * b4;
    }
  }
  __shared__ float red[15][4];
  int wave = tid >> 6, lane = tid & 63;
#pragma unroll
  for (int k = 0; k < 15; k++) {
    float v = s[k];
    for (int d = 32; d; d >>= 1) v += __shfl_xor(v, d);
    if (lane == 0) red[k][wave] = v;
  }
  __syncthreads();
  if (tid < 15)
    diags[(size_t)(tid + 1) * NN + row] =
        (red[tid][0] + red[tid][1] + red[tid][2] + red[tid][3]) * FP8_IS2;
}

// ---------------- fp16 MFMA node GEMM: C[M][Nn] = A @ Bt^T + bias (+skip on hi cols) ----
__global__ __launch_bounds__(256) void gemm_f16_node(const _Float16* __restrict__ A,
                                                     const _Float16* __restrict__ Bt,
                                                     const float* __restrict__ bias,
                                                     const float* __restrict__ addhi,
                                                     float* __restrict__ C32,
                                                     _Float16* __restrict__ C16,
                                                     int M, int Nn, int K) {
  __shared__ _Float16 As[64 * 32];
  __shared__ _Float16 Bs[64 * 32];
  const int tid = threadIdx.x;
  const int lane = tid & 63, wave = tid >> 6;
  const int wr = wave >> 1, wc = wave & 1;
  const int m0 = blockIdx.y * 64, n0 = blockIdx.x * 64;
  const int fr = lane & 15, fk = (lane >> 4) * 8;
  const int gr = tid >> 2, gc = (tid & 3) * 8;
  f32x4 acc[2][2] = {};
  for (int k0 = 0; k0 < K; k0 += 32) {
    gload16(A + (size_t)(m0 + gr) * K + k0 + gc, As + tid * 8);
    gload16(Bt + (size_t)(n0 + gr) * K + k0 + gc, Bs + tid * 8);
    __syncthreads();
    f16x8 af[2], bf[2];
#pragma unroll
    for (int i = 0; i < 2; i++) {
      af[i] = *(const f16x8*)(As + (wr * 32 + i * 16 + fr) * 32 + fk);
      bf[i] = *(const f16x8*)(Bs + (wc * 32 + i * 16 + fr) * 32 + fk);
    }
#pragma unroll
    for (int i = 0; i < 2; i++)
#pragma unroll
      for (int j = 0; j < 2; j++)
        acc[i][j] = __builtin_amdgcn_mfma_f32_16x16x32_f16(af[i], bf[j], acc[i][j], 0, 0, 0);
    __syncthreads();
  }
  const int crow0 = m0 + wr * 32, ccol0 = n0 + wc * 32;
#pragma unroll
  for (int i = 0; i < 2; i++)
#pragma unroll
    for (int j = 0; j < 2; j++)
#pragma unroll
      for (int r = 0; r < 4; r++) {
        int row = crow0 + i * 16 + (lane >> 4) * 4 + r;
        int col = ccol0 + j * 16 + (lane & 15);
        float val = acc[i][j][r];
        if (bias) val += bias[col];
        if (addhi && col >= Nn - 256) val += addhi[(size_t)row * 256 + col - (Nn - 256)];
        if (C32) C32[(size_t)row * Nn + col] = val;
        if (C16) C16[(size_t)row * Nn + col] = (_Float16)val;
      }
}

// proj weight: [CATK][HID] f32 -> [HID][KPAD] f16
__global__ void wconv_proj_kernel(const float* __restrict__ W, _Float16* __restrict__ Wt) {
  int idx = blockIdx.x * 256 + threadIdx.x;
  if (idx >= HID * KPAD) return;
  int n = idx / KPAD, k = idx - n * KPAD;
  Wt[idx] = (k < CATK) ? (_Float16)W[(size_t)k * HID + n] : (_Float16)0.f;
}

// per-layer: Wq|Wk|Wv|Ws -> wt_cat [1024][256] f16; biases -> bcat[1024]
__global__ void wconv_cat_kernel(const float* __restrict__ Wq, const float* __restrict__ Wk,
                                 const float* __restrict__ Wv, const float* __restrict__ Wsk,
                                 const float* __restrict__ bq, const float* __restrict__ bk,
                                 const float* __restrict__ bv, const float* __restrict__ bsk,
                                 _Float16* __restrict__ wt, float* __restrict__ bcat) {
  int idx = blockIdx.x * 256 + threadIdx.x;
  if (idx < 1024) {
    int s = idx >> 8, j = idx & 255;
    bcat[idx] = (s == 0) ? bq[j] : (s == 1) ? bk[j] : (s == 2) ? bv[j] : bsk[j];
  }
  if (idx < 4 * HID * HID) {
    int nrow = idx >> 8, k = idx & 255;
    int s = nrow >> 8, nc = nrow & 255;
    const float* W = (s == 0) ? Wq : (s == 1) ? Wk : (s == 2) ? Wv : Wsk;
    wt[idx] = (_Float16)W[(size_t)k * HID + nc];
  }
}

// concat with inline PE
__global__ void concat16_kernel(const float* __restrict__ x, const float* __restrict__ diags,
                                const float* __restrict__ w, const float* __restrict__ bb,
                                _Float16* __restrict__ xc) {
  int idx = blockIdx.x * 256 + threadIdx.x;
  if (idx >= NN * KPAD) return;
  int i = idx / KPAD, c = idx - i * KPAD;
  float v;
  if (c < INCH) v = x[(size_t)i * INCH + c];
  else if (c < CATK) {
    int d = c - INCH;
    v = bb[d];
#pragma unroll
    for (int t = 0; t < 16; t++) v += diags[t * NN + i] * w[t * 16 + d];
  } else v = 0.f;
  xc[idx] = (_Float16)v;
}

// ---------------- CSR ----------------
__global__ void csr_scan_kernel(const int* __restrict__ cnt, int* __restrict__ off) {
  int lane = threadIdx.x;  // single wave
  const int per = NN / 64;
  int s = 0;
  for (int i = 0; i < per; i++) s += cnt[lane * per + i];
  int run = s;
  for (int d = 1; d < 64; d <<= 1) {
    int t = __shfl_up(run, d);
    if (lane >= d) run += t;
  }
  int acc = run - s;
  for (int i = 0; i < per; i++) {
    off[lane * per + i] = acc;
    acc += cnt[lane * per + i];
  }
  if (lane == 63) off[NN] = acc;
}

__global__ void csr_fill_kernel(const int* __restrict__ sidx, const int* __restrict__ tidx,
                                const int* __restrict__ off, int* __restrict__ cur,
                                int* __restrict__ csrc) {
  int e = blockIdx.x * 256 + threadIdx.x;
  if (e >= NE) return;
  int t = tidx[e];
  int pos = atomicAdd(&cur[t], 1);
  csrc[off[t] + pos] = sidx[e];
}

// ---------------- fused attention + LayerNorm + ReLU, two-phase ----------------
__global__ __launch_bounds__(256) void attn_ln_kernel(const int* __restrict__ off,
                                                      const int* __restrict__ csrc,
                                                      const _Float16* __restrict__ qkvz,
                                                      const float* __restrict__ g,
                                                      const float* __restrict__ b,
                                                      float* __restrict__ hb,
                                                      _Float16* __restrict__ h16) {
  int node = blockIdx.x, tid = threadIdx.x;
  int h = tid >> 6, lane = tid & 63;
  int beg = off[node], end = off[node + 1];
  __shared__ _Float16 qs[256];
  __shared__ int srcs[MAXE];
  __shared__ float ps[4][MAXE];
  qs[tid] = qkvz[(size_t)node * 1024 + tid];
  float m_run = -INFINITY, d_run = 0.f, acc = 0.f;
  for (int chunk = beg; chunk < end; chunk += MAXE) {
    int ne = min(end - chunk, MAXE);
    if (tid < ne) srcs[tid] = csrc[chunk + tid];
    __syncthreads();
    // scores
    for (int p = tid; p < ne * 4; p += 256) {
      int e = p >> 2, h2 = p & 3;
      const f16x8* krow = (const f16x8*)(qkvz + (size_t)srcs[e] * 1024 + 256 + h2 * 64);
      const f16x8* qrow = (const f16x8*)(qs + h2 * 64);
      float sc = 0.f;
#pragma unroll
      for (int d8 = 0; d8 < 8; d8++) {
        f16x8 kv = krow[d8], qv = qrow[d8];
#pragma unroll
        for (int r = 0; r < 8; r++) sc += (float)qv[r] * (float)kv[r];
      }
      ps[h2][e] = sc * 0.125f;
    }
    __syncthreads();
    // per-head max
    float mloc = -INFINITY;
    for (int e = lane; e < ne; e += 64) mloc = fmaxf(mloc, ps[h][e]);
    for (int d = 32; d; d >>= 1) mloc = fmaxf(mloc, __shfl_xor(mloc, d));
    float mnew = fmaxf(m_run, mloc);
    // exp in place + denom
    float dloc = 0.f;
    for (int e = lane; e < ne; e += 64) {
      float p = __expf(ps[h][e] - mnew);
      ps[h][e] = p;
      dloc += p;
    }
    for (int d = 32; d; d >>= 1) dloc += __shfl_xor(dloc, d);
    float scale = __expf(m_run - mnew);   // exp(-inf)=0 on first chunk
    d_run = d_run * scale + dloc;
    acc *= scale;
    // V accumulate (iterations independent -> memory ILP)
    for (int e = 0; e < ne; e++) {
      acc += ps[h][e] * (float)qkvz[(size_t)srcs[e] * 1024 + 512 + h * 64 + lane];
    }
    m_run = mnew;
    __syncthreads();
  }
  float agg = acc / fmaxf(d_run, 1e-16f);
  float z = (float)qkvz[(size_t)node * 1024 + 768 + tid] + agg;
  // LayerNorm over 256
  float s = z;
  for (int d = 32; d; d >>= 1) s += __shfl_xor(s, d);
  __shared__ float w4[4], w4b[4];
  if (lane == 0) w4[h] = s;
  __syncthreads();
  float mu = (w4[0] + w4[1] + w4[2] + w4[3]) * (1.f / HID);
  float dv = z - mu;
  float qv = dv * dv;
  for (int d = 32; d; d >>= 1) qv += __shfl_xor(qv, d);
  if (lane == 0) w4b[h] = qv;
  __syncthreads();
  float var = (w4b[0] + w4b[1] + w4b[2] + w4b[3]) * (1.f / HID);
  float y = dv * (1.f / sqrtf(var + 1e-5f)) * g[tid] + b[tid];
  y = fmaxf(y, 0.f);
  hb[(size_t)node * HID + tid] = y;
  h16[(size_t)node * HID + tid] = (_Float16)y;
}

// decode from fp16 h (halves L2 gather traffic; error << bf16 quantization floor)
__global__ void decode_kernel(const _Float16* __restrict__ h, const int* __restrict__ src,
                              const int* __restrict__ dst, float* __restrict__ out) {
  int wv = threadIdx.x >> 6, lane = threadIdx.x & 63;
  int p = blockIdx.x * 4 + wv;
  if (p >= NP) return;
  const f16x4* a = (const f16x4*)(h + (size_t)src[p] * HID);
  const f16x4* b = (const f16x4*)(h + (size_t)dst[p] * HID);
  f16x4 x = a[lane], y = b[lane];
  float s = (float)x[0] * (float)y[0] + (float)x[1] * (float)y[1] +
            (float)x[2] * (float)y[2] + (float)x[3] * (float)y[3];
  for (int d = 32; d; d >>= 1) s += __shfl_xor(s, d);
  if (lane == 0) out[p] = 1.f / (1.f + expf(-s));
}

// ---------------- host launch ----------------
extern "C" void kernel_launch(void* const* d_in, const int* in_sizes, int n_in,
                              void* d_out, int out_size, void* d_ws, size_t ws_size,
                              hipStream_t stream) {
  const float* x      = (const float*)d_in[0];
  const int*   ei     = (const int*)d_in[1];
  const int*   src    = (const int*)d_in[2];
  const int*   dst    = (const int*)d_in[3];
  const float* rwse_w = (const float*)d_in[4];
  const float* rwse_b = (const float*)d_in[5];
  const float* proj_w = (const float*)d_in[6];
  const float* proj_b = (const float*)d_in[7];
  const float* Wq     = (const float*)d_in[8];
  const float* bq     = (const float*)d_in[9];
  const float* Wk     = (const float*)d_in[10];
  const float* bk     = (const float*)d_in[11];
  const float* Wv     = (const float*)d_in[12];
  const float* bv     = (const float*)d_in[13];
  const float* Wsk    = (const float*)d_in[14];
  const float* bs     = (const float*)d_in[15];
  const float* ln_g   = (const float*)d_in[16];
  const float* ln_b   = (const float*)d_in[17];
  float* out = (float*)d_out;

  const size_t M8 = (size_t)NN * NN;    // 9,437,184 bytes per fp8 matrix
  char* base = (char*)d_ws;
  unsigned char* rw   = (unsigned char*)(base + 0 * M8);
  unsigned char* rwT  = (unsigned char*)(base + 1 * M8);
  unsigned char* rw2  = (unsigned char*)(base + 2 * M8);
  unsigned char* rw3  = (unsigned char*)(base + 3 * M8);
  unsigned char* rw4  = (unsigned char*)(base + 4 * M8);
  unsigned char* rw4T = (unsigned char*)(base + 5 * M8);
  unsigned char* rw8  = (unsigned char*)(base + 6 * M8);
  unsigned char* rw12 = (unsigned char*)(base + 7 * M8);
  unsigned char* rw2T = (unsigned char*)(base + 8 * M8);
  unsigned char* rw3T = (unsigned char*)(base + 9 * M8);
  float* adj = (float*)(base + 6 * M8);  // f32 [NN][NN] = 4 fp8 slots (6..9); dead before rw8 written
  char* sm = base + 10 * M8;
  float* diags = (float*)sm; sm += (size_t)16 * NN * 4;
  int* cnt = (int*)sm; sm += 12288;
  int* cur = (int*)sm; sm += 12288;
  int* off = (int*)sm; sm += 16384;
  int* csrc = (int*)sm; sm += (size_t)NE * 4;
  float* hbuf = (float*)sm; sm += (size_t)NN * HID * 4;
  _Float16* qkvz16 = (_Float16*)sm; sm += (size_t)NN * 1024 * 2;
  _Float16* h16  = (_Float16*)sm; sm += (size_t)NN * HID * 2;
  _Float16* xc16 = (_Float16*)sm; sm += (size_t)NN * KPAD * 2;
  _Float16* wt_proj = (_Float16*)sm; sm += (size_t)HID * KPAD * 2;
  _Float16* wt_cat[2]; float* bcat[2];
  for (int l = 0; l < 2; ++l) {
    wt_cat[l] = (_Float16*)sm; sm += (size_t)4 * HID * HID * 2;
    bcat[l]   = (float*)sm;    sm += 1024 * 4;
  }
  (void)in_sizes; (void)n_in; (void)out_size; (void)ws_size;

  const dim3 B256(256);
  const dim3 gT1(NN / 64, NN / 64, 1);
  const dim3 gT2(NN / 64, NN / 64, 2);
  const int  gG = (NN / 128) * (NN / 128);     // 576
  const dim3 gW(1024 / 64, NN / 64);
  const dim3 gS(HID / 64, NN / 64);

  // --- weight prep ---
  wconv_proj_kernel<<<(HID * KPAD + 255) / 256, B256, 0, stream>>>(proj_w, wt_proj);
  for (int l = 0; l < 2; ++l)
    wconv_cat_kernel<<<(4 * HID * HID + 255) / 256, B256, 0, stream>>>(
        Wq + (size_t)l * HID * HID, Wk + (size_t)l * HID * HID, Wv + (size_t)l * HID * HID,
        Wsk + (size_t)l * HID * HID, bq + l * HID, bk + l * HID, bv + l * HID, bs + l * HID,
        wt_cat[l], bcat[l]);

  // --- adjacency + in-degree + CSR ---
  hipMemsetAsync(adj, 0, (size_t)NN * NN * 4, stream);
  hipMemsetAsync(cnt, 0, 24576, stream);   // cnt + cur contiguous
  edges_kernel<<<(NE + 255) / 256, B256, 0, stream>>>(ei, adj, cnt);
  rownorm_kernel<<<NN, B256, 0, stream>>>(adj, rw, diags);
  csr_scan_kernel<<<1, 64, 0, stream>>>(cnt, off);
  csr_fill_kernel<<<(NE + 255) / 256, B256, 0, stream>>>(ei, ei + NE, off, cur, csrc);

  // --- RWSE power chain (fp8, uniformly scaled by FP8_S) ---
  transpose2_u8_kernel<<<gT1, B256, 0, stream>>>(rw, rwT, rw, rwT);
  gemm_fp8_nt<<<gG, B256, 0, stream>>>(rw, rwT, rw2, NN);    // rw2 = rw*rw
  gemm_fp8_nt<<<gG, B256, 0, stream>>>(rw2, rwT, rw3, NN);   // rw3 = rw2*rw
  gemm_fp8_nt<<<gG, B256, 0, stream>>>(rw3, rwT, rw4, NN);   // rw4 = rw3*rw
  transpose2_u8_kernel<<<gT1, B256, 0, stream>>>(rw4, rw4T, rw4, rw4T);
  gemm_fp8_nt<<<gG, B256, 0, stream>>>(rw4, rw4T, rw8, NN);  // rw8 = rw4*rw4
  gemm_fp8_nt<<<gG, B256, 0, stream>>>(rw8, rw4T, rw12, NN); // rw12 = rw8*rw4
  transpose2_u8_kernel<<<gT2, B256, 0, stream>>>(rw2, rw2T, rw3, rw3T);
  diag_all_kernel<<<NN, B256, 0, stream>>>(rw, rw2, rw4, rw8, rw12,
                                           rwT, rw2T, rw3T, rw4T, diags);

  // --- input projection (PE inline in concat) ---
  concat16_kernel<<<(NN * KPAD + 255) / 256, B256, 0, stream>>>(x, diags, rwse_w, rwse_b, xc16);
  gemm_f16_node<<<gS, B256, 0, stream>>>(xc16, wt_proj, proj_b, nullptr, hbuf, h16,
                                         NN, HID, KPAD);

  // --- transformer layers ---
  for (int l = 0; l < 2; ++l) {
    gemm_f16_node<<<gW, B256, 0, stream>>>(h16, wt_cat[l], bcat[l], hbuf, nullptr, qkvz16,
                                           NN, 1024, HID);
    attn_ln_kernel<<<NN, B256, 0, stream>>>(off, csrc, qkvz16, ln_g + l * HID, ln_b + l * HID,
                                            hbuf, h16);
  }

  decode_kernel<<<NP / 4, B256, 0, stream>>>(h16, src, dst, out);
}

// Round 9
// 500.790 us; speedup vs baseline: 1.4361x; 1.0389x over previous
//
#include <hip/hip_runtime.h>
#include <hip/hip_bf16.h>
#include <hip/hip_fp8.h>

#define NN   3072
#define NE   147456
#define NP   100000
#define HID  256
#define INCH 128
#define CATK 144
#define KPAD 160
#define FP8_S    1024.0f
#define FP8_IS   (1.0f / 1024.0f)
#define FP8_IS2  (1.0f / (1024.0f * 1024.0f))
#define MAXE 128

typedef __attribute__((ext_vector_type(4))) float    f32x4;
typedef __attribute__((ext_vector_type(8))) _Float16 f16x8;
typedef __attribute__((ext_vector_type(4))) _Float16 f16x4;
typedef __attribute__((ext_vector_type(8))) unsigned char u8x8;
typedef __attribute__((ext_vector_type(4))) int i32x4;
typedef __attribute__((ext_vector_type(8))) int i32x8;

__device__ __forceinline__ float fp8f(unsigned char b) {
  __hip_fp8_e4m3 t; t.__x = b; return (float)t;
}
__device__ __forceinline__ unsigned char f2fp8(float v) {
  __hip_fp8_e4m3 t(v); return t.__x;
}

// ---------------- async global->LDS (16B) ----------------
__device__ __forceinline__ void gload16(const void* g, void* l) {
  __builtin_amdgcn_global_load_lds((const __attribute__((address_space(1))) void*)g,
                                   (__attribute__((address_space(3))) void*)l, 16, 0, 0);
}

// ---------------- K1: edges (adj scatter + indeg) | wconv proj | wconv cat x2 ----------------
__global__ void prep_kernel(const int* __restrict__ ei, float* __restrict__ adj,
                            int* __restrict__ cnt,
                            const float* __restrict__ proj_w, _Float16* __restrict__ wt_proj,
                            const float* __restrict__ Wq, const float* __restrict__ Wk,
                            const float* __restrict__ Wv, const float* __restrict__ Wsk,
                            const float* __restrict__ bq, const float* __restrict__ bk,
                            const float* __restrict__ bv, const float* __restrict__ bsk,
                            _Float16* __restrict__ wt_cat0, _Float16* __restrict__ wt_cat1,
                            float* __restrict__ bcat0, float* __restrict__ bcat1) {
  int bid = blockIdx.x, tid = threadIdx.x;
  if (bid < 576) {                       // edges
    int e = bid * 256 + tid;
    if (e < NE) {
      int s = ei[e], t = ei[NE + e];
      atomicAdd(&adj[(size_t)s * NN + t], 1.0f);
      atomicAdd(&cnt[t], 1);
    }
    return;
  }
  if (bid < 736) {                       // wconv proj: [CATK][HID] f32 -> [HID][KPAD] f16
    int idx = (bid - 576) * 256 + tid;
    if (idx < HID * KPAD) {
      int n = idx / KPAD, k = idx - n * KPAD;
      wt_proj[idx] = (k < CATK) ? (_Float16)proj_w[(size_t)k * HID + n] : (_Float16)0.f;
    }
    return;
  }
  int l = (bid < 1760) ? 0 : 1;
  int idx = (bid - (l ? 1760 : 736)) * 256 + tid;
  const float* Wq_ = Wq + (size_t)l * HID * HID;
  const float* Wk_ = Wk + (size_t)l * HID * HID;
  const float* Wv_ = Wv + (size_t)l * HID * HID;
  const float* Ws_ = Wsk + (size_t)l * HID * HID;
  _Float16* wt = l ? wt_cat1 : wt_cat0;
  float* bcat = l ? bcat1 : bcat0;
  if (idx < 1024) {
    int s = idx >> 8, j = idx & 255;
    bcat[idx] = (s == 0) ? bq[l * HID + j] : (s == 1) ? bk[l * HID + j]
              : (s == 2) ? bv[l * HID + j] : bsk[l * HID + j];
  }
  if (idx < 4 * HID * HID) {
    int nrow = idx >> 8, k = idx & 255;
    int s = nrow >> 8, nc = nrow & 255;
    const float* W = (s == 0) ? Wq_ : (s == 1) ? Wk_ : (s == 2) ? Wv_ : Ws_;
    wt[idx] = (_Float16)W[(size_t)k * HID + nc];
  }
}

// ---------------- K2: rownorm (3072 blocks) | csr_scan (1 block) ----------------
__global__ void rownorm_scan_kernel(const float* __restrict__ adj, unsigned char* __restrict__ rw,
                                    float* __restrict__ diag1,
                                    const int* __restrict__ cnt, int* __restrict__ off) {
  int bid = blockIdx.x, tid = threadIdx.x;
  if (bid < NN) {
    const float* ap = adj + (size_t)bid * NN;
    float s = 0.f;
    for (int j = tid; j < NN; j += 256) s += ap[j];
    for (int d = 32; d; d >>= 1) s += __shfl_xor(s, d);
    __shared__ float w4[4];
    if ((tid & 63) == 0) w4[tid >> 6] = s;
    __syncthreads();
    float inv = 1.f / fmaxf(w4[0] + w4[1] + w4[2] + w4[3], 1.f);
    unsigned char* rp = rw + (size_t)bid * NN;
    for (int j = tid; j < NN; j += 256) {
      float v = ap[j] * inv;
      rp[j] = f2fp8(v * FP8_S);
      if (j == bid) diag1[bid] = v;
    }
    return;
  }
  if (tid >= 64) return;                 // csr exclusive scan, single wave
  int lane = tid;
  const int per = NN / 64;
  int s = 0;
  for (int i = 0; i < per; i++) s += cnt[lane * per + i];
  int run = s;
  for (int d = 1; d < 64; d <<= 1) {
    int t = __shfl_up(run, d);
    if (lane >= d) run += t;
  }
  int acc = run - s;
  for (int i = 0; i < per; i++) {
    off[lane * per + i] = acc;
    acc += cnt[lane * per + i];
  }
  if (lane == 63) off[NN] = acc;
}

// ---------------- u8 64x64 transpose body ----------------
__device__ __forceinline__ void transpose_body(const unsigned char* __restrict__ in,
                                               unsigned char* __restrict__ out,
                                               int bx, int by, int tid) {
  __shared__ unsigned char t[64][68];
#pragma unroll
  for (int ii = 0; ii < 4; ii++) {
    int lin = ii * 256 + tid;
    int r = lin >> 4, c4 = (lin & 15) * 4;
    unsigned int v = *(const unsigned int*)(in + (size_t)(by * 64 + r) * NN + bx * 64 + c4);
    t[r][c4] = v & 255; t[r][c4 + 1] = (v >> 8) & 255;
    t[r][c4 + 2] = (v >> 16) & 255; t[r][c4 + 3] = v >> 24;
  }
  __syncthreads();
#pragma unroll
  for (int ii = 0; ii < 4; ii++) {
    int lin = ii * 256 + tid;
    int r = lin >> 4, c4 = (lin & 15) * 4;
    unsigned int v = (unsigned int)t[c4][r] | ((unsigned int)t[c4 + 1][r] << 8) |
                     ((unsigned int)t[c4 + 2][r] << 16) | ((unsigned int)t[c4 + 3][r] << 24);
    *(unsigned int*)(out + (size_t)(bx * 64 + r) * NN + by * 64 + c4) = v;
  }
}

// ---------------- K3: csr_fill (576 blocks) | transpose rw->rwT (2304 blocks) ----------------
__global__ void fill_transpose_kernel(const int* __restrict__ sidx, const int* __restrict__ tidx,
                                      const int* __restrict__ off, int* __restrict__ cur,
                                      int* __restrict__ csrc,
                                      const unsigned char* __restrict__ rw,
                                      unsigned char* __restrict__ rwT) {
  int bid = blockIdx.x, tid = threadIdx.x;
  if (bid < 576) {
    int e = bid * 256 + tid;
    if (e < NE) {
      int t = tidx[e];
      int pos = atomicAdd(&cur[t], 1);
      csrc[off[t] + pos] = sidx[e];
    }
    return;
  }
  int t = bid - 576;
  transpose_body(rw, rwT, t % 48, t / 48, tid);
}

// ---------------- transpose x3 via blockIdx.z: rw4T, rw2T, rw3T ----------------
__global__ void transpose3_kernel(const unsigned char* __restrict__ rw4, unsigned char* __restrict__ rw4T,
                                  const unsigned char* __restrict__ rw2, unsigned char* __restrict__ rw2T,
                                  const unsigned char* __restrict__ rw3, unsigned char* __restrict__ rw3T) {
  const unsigned char* in  = (blockIdx.z == 0) ? rw4  : (blockIdx.z == 1) ? rw2  : rw3;
  unsigned char* out       = (blockIdx.z == 0) ? rw4T : (blockIdx.z == 1) ? rw2T : rw3T;
  transpose_body(in, out, blockIdx.x, blockIdx.y, threadIdx.x);
}

// ---------------- MX-fp8 MFMA GEMM: C = A * Bt^T (all scaled by FP8_S) ----------------
// 128x128 tile, BK=128, 4 waves, XOR-swizzled LDS (16B chunk ^= row&7),
// XCD-chunked block swizzle. mfma_scale_f32_16x16x128_f8f6f4, E8M0 scale=127 (1.0).
// R4 lesson: no epilogue grafts. R8-proven at 43.2 us/dispatch.
__global__ __launch_bounds__(256) void gemm_fp8_nt(const unsigned char* __restrict__ A,
                                                   const unsigned char* __restrict__ Bt,
                                                   unsigned char* __restrict__ C, int n) {
  __shared__ __align__(16) unsigned char As[128 * 128];
  __shared__ __align__(16) unsigned char Bs[128 * 128];
  const int nbx = n >> 7;
  const int nb = nbx * nbx;
  const int bid = blockIdx.x;
  const int cpx = nb >> 3;
  const int wg = (bid & 7) * cpx + (bid >> 3);
  const int by = wg / nbx, bx = wg % nbx;
  const int tid = threadIdx.x;
  const int lane = tid & 63, wave = tid >> 6;
  const int wr = wave >> 1, wc = wave & 1;
  const int rowA0 = by * 128, rowB0 = bx * 128;
  const int fr = lane & 15;
  const int kg = lane >> 4;
  const int sr = tid >> 3;
  const int scd = tid & 7;
  f32x4 acc[4][4] = {};
  const int nkt = n >> 7;
  for (int kt = 0; kt < nkt; ++kt) {
    const int k0 = kt << 7;
#pragma unroll
    for (int s = 0; s < 4; s++) {
      const int row = sr + s * 32;
      const int cg = (scd ^ (row & 7)) << 4;
      gload16(A + (size_t)(rowA0 + row) * n + k0 + cg, As + row * 128 + scd * 16);
      gload16(Bt + (size_t)(rowB0 + row) * n + k0 + cg, Bs + row * 128 + scd * 16);
    }
    __syncthreads();
    i32x8 af[4], bf[4];
#pragma unroll
    for (int i = 0; i < 4; i++) {
      const int Ra = wr * 64 + i * 16 + fr;
      const int Rb = wc * 64 + i * 16 + fr;
      const int c0a = ((2 * kg) ^ (Ra & 7)) << 4, c1a = ((2 * kg + 1) ^ (Ra & 7)) << 4;
      const int c0b = ((2 * kg) ^ (Rb & 7)) << 4, c1b = ((2 * kg + 1) ^ (Rb & 7)) << 4;
      i32x4 alo = *(const i32x4*)(As + Ra * 128 + c0a);
      i32x4 ahi = *(const i32x4*)(As + Ra * 128 + c1a);
      i32x4 blo = *(const i32x4*)(Bs + Rb * 128 + c0b);
      i32x4 bhi = *(const i32x4*)(Bs + Rb * 128 + c1b);
      af[i] = (i32x8){alo[0], alo[1], alo[2], alo[3], ahi[0], ahi[1], ahi[2], ahi[3]};
      bf[i] = (i32x8){blo[0], blo[1], blo[2], blo[3], bhi[0], bhi[1], bhi[2], bhi[3]};
    }
#pragma unroll
    for (int i = 0; i < 4; i++)
#pragma unroll
      for (int j = 0; j < 4; j++)
        acc[i][j] = __builtin_amdgcn_mfma_scale_f32_16x16x128_f8f6f4(
            af[i], bf[j], acc[i][j], 0, 0, 0, 127, 0, 127);
    __syncthreads();
  }
  const int crow0 = rowA0 + wr * 64, ccol0 = rowB0 + wc * 64;
#pragma unroll
  for (int i = 0; i < 4; i++)
#pragma unroll
    for (int j = 0; j < 4; j++)
#pragma unroll
      for (int r = 0; r < 4; r++) {
        int row = crow0 + i * 16 + (lane >> 4) * 4 + r;
        int col = ccol0 + j * 16 + (lane & 15);
        C[(size_t)row * n + col] = f2fp8(acc[i][j][r] * FP8_IS);
      }
}

// ---------------- all diagonals t=2..16 in one streaming pass (fp8 inputs) ----------
__global__ __launch_bounds__(256) void diag_all_kernel(
    const unsigned char* __restrict__ rw, const unsigned char* __restrict__ rw2,
    const unsigned char* __restrict__ rw4, const unsigned char* __restrict__ rw8,
    const unsigned char* __restrict__ rw12, const unsigned char* __restrict__ rwT,
    const unsigned char* __restrict__ rw2T, const unsigned char* __restrict__ rw3T,
    const unsigned char* __restrict__ rw4T, float* __restrict__ diags) {
  int row = blockIdx.x, tid = threadIdx.x;
  size_t base = (size_t)row * NN;
  const u8x8* pl1  = (const u8x8*)(rw + base);
  const u8x8* pl2  = (const u8x8*)(rw2 + base);
  const u8x8* pl4  = (const u8x8*)(rw4 + base);
  const u8x8* pl8  = (const u8x8*)(rw8 + base);
  const u8x8* pl12 = (const u8x8*)(rw12 + base);
  const u8x8* pr1  = (const u8x8*)(rwT + base);
  const u8x8* pr2  = (const u8x8*)(rw2T + base);
  const u8x8* pr3  = (const u8x8*)(rw3T + base);
  const u8x8* pr4  = (const u8x8*)(rw4T + base);
  float s[15];
#pragma unroll
  for (int k = 0; k < 15; k++) s[k] = 0.f;
  for (int j = tid; j < NN / 8; j += 256) {
    u8x8 L1 = pl1[j], L2 = pl2[j], L4 = pl4[j], L8 = pl8[j], L12 = pl12[j];
    u8x8 R1 = pr1[j], R2 = pr2[j], R3 = pr3[j], R4 = pr4[j];
#pragma unroll
    for (int r = 0; r < 8; r++) {
      float a1 = fp8f(L1[r]), a2 = fp8f(L2[r]), a4 = fp8f(L4[r]),
            a8 = fp8f(L8[r]), a12 = fp8f(L12[r]);
      float b1 = fp8f(R1[r]), b2 = fp8f(R2[r]), b3 = fp8f(R3[r]), b4 = fp8f(R4[r]);
      s[0]  += a1 * b1;  s[1]  += a2 * b1;  s[2]  += a2 * b2;
      s[3]  += a4 * b1;  s[4]  += a4 * b2;  s[5]  += a4 * b3;  s[6]  += a4 * b4;
      s[7]  += a8 * b1;  s[8]  += a8 * b2;  s[9]  += a8 * b3;  s[10] += a8 * b4;
      s[11] += a12 * b1; s[12] += a12 * b2; s[13] += a12 * b3; s[14] += a12 * b4;
    }
  }
  __shared__ float red[15][4];
  int wave = tid >> 6, lane = tid & 63;
#pragma unroll
  for (int k = 0; k < 15; k++) {
    float v = s[k];
    for (int d = 32; d; d >>= 1) v += __shfl_xor(v, d);
    if (lane == 0) red[k][wave] = v;
  }
  __syncthreads();
  if (tid < 15)
    diags[(size_t)(tid + 1) * NN + row] =
        (red[tid][0] + red[tid][1] + red[tid][2] + red[tid][3]) * FP8_IS2;
}

// ---------------- fp16 MFMA node GEMM: C16[M][Nn] = A @ Bt^T + bias (+f16 skip on hi cols) ----
__global__ __launch_bounds__(256) void gemm_f16_node(const _Float16* __restrict__ A,
                                                     const _Float16* __restrict__ Bt,
                                                     const float* __restrict__ bias,
                                                     const _Float16* __restrict__ addhi,
                                                     _Float16* __restrict__ C16,
                                                     int M, int Nn, int K) {
  __shared__ _Float16 As[64 * 32];
  __shared__ _Float16 Bs[64 * 32];
  const int tid = threadIdx.x;
  const int lane = tid & 63, wave = tid >> 6;
  const int wr = wave >> 1, wc = wave & 1;
  const int m0 = blockIdx.y * 64, n0 = blockIdx.x * 64;
  const int fr = lane & 15, fk = (lane >> 4) * 8;
  const int gr = tid >> 2, gc = (tid & 3) * 8;
  f32x4 acc[2][2] = {};
  for (int k0 = 0; k0 < K; k0 += 32) {
    gload16(A + (size_t)(m0 + gr) * K + k0 + gc, As + tid * 8);
    gload16(Bt + (size_t)(n0 + gr) * K + k0 + gc, Bs + tid * 8);
    __syncthreads();
    f16x8 af[2], bf[2];
#pragma unroll
    for (int i = 0; i < 2; i++) {
      af[i] = *(const f16x8*)(As + (wr * 32 + i * 16 + fr) * 32 + fk);
      bf[i] = *(const f16x8*)(Bs + (wc * 32 + i * 16 + fr) * 32 + fk);
    }
#pragma unroll
    for (int i = 0; i < 2; i++)
#pragma unroll
      for (int j = 0; j < 2; j++)
        acc[i][j] = __builtin_amdgcn_mfma_f32_16x16x32_f16(af[i], bf[j], acc[i][j], 0, 0, 0);
    __syncthreads();
  }
  const int crow0 = m0 + wr * 32, ccol0 = n0 + wc * 32;
#pragma unroll
  for (int i = 0; i < 2; i++)
#pragma unroll
    for (int j = 0; j < 2; j++)
#pragma unroll
      for (int r = 0; r < 4; r++) {
        int row = crow0 + i * 16 + (lane >> 4) * 4 + r;
        int col = ccol0 + j * 16 + (lane & 15);
        float val = acc[i][j][r];
        if (bias) val += bias[col];
        if (addhi && col >= Nn - 256) val += (float)addhi[(size_t)row * 256 + col - (Nn - 256)];
        C16[(size_t)row * Nn + col] = (_Float16)val;
      }
}

// concat with inline PE
__global__ void concat16_kernel(const float* __restrict__ x, const float* __restrict__ diags,
                                const float* __restrict__ w, const float* __restrict__ bb,
                                _Float16* __restrict__ xc) {
  int idx = blockIdx.x * 256 + threadIdx.x;
  if (idx >= NN * KPAD) return;
  int i = idx / KPAD, c = idx - i * KPAD;
  float v;
  if (c < INCH) v = x[(size_t)i * INCH + c];
  else if (c < CATK) {
    int d = c - INCH;
    v = bb[d];
#pragma unroll
    for (int t = 0; t < 16; t++) v += diags[t * NN + i] * w[t * 16 + d];
  } else v = 0.f;
  xc[idx] = (_Float16)v;
}

// ---------------- fused attention + LayerNorm + ReLU, two-phase ----------------
__global__ __launch_bounds__(256) void attn_ln_kernel(const int* __restrict__ off,
                                                      const int* __restrict__ csrc,
                                                      const _Float16* __restrict__ qkvz,
                                                      const float* __restrict__ g,
                                                      const float* __restrict__ b,
                                                      _Float16* __restrict__ h16) {
  int node = blockIdx.x, tid = threadIdx.x;
  int h = tid >> 6, lane = tid & 63;
  int beg = off[node], end = off[node + 1];
  __shared__ _Float16 qs[256];
  __shared__ int srcs[MAXE];
  __shared__ float ps[4][MAXE];
  qs[tid] = qkvz[(size_t)node * 1024 + tid];
  float m_run = -INFINITY, d_run = 0.f, acc = 0.f;
  for (int chunk = beg; chunk < end; chunk += MAXE) {
    int ne = min(end - chunk, MAXE);
    if (tid < ne) srcs[tid] = csrc[chunk + tid];
    __syncthreads();
    // scores
    for (int p = tid; p < ne * 4; p += 256) {
      int e = p >> 2, h2 = p & 3;
      const f16x8* krow = (const f16x8*)(qkvz + (size_t)srcs[e] * 1024 + 256 + h2 * 64);
      const f16x8* qrow = (const f16x8*)(qs + h2 * 64);
      float sc = 0.f;
#pragma unroll
      for (int d8 = 0; d8 < 8; d8++) {
        f16x8 kv = krow[d8], qv = qrow[d8];
#pragma unroll
        for (int r = 0; r < 8; r++) sc += (float)qv[r] * (float)kv[r];
      }
      ps[h2][e] = sc * 0.125f;
    }
    __syncthreads();
    // per-head max
    float mloc = -INFINITY;
    for (int e = lane; e < ne; e += 64) mloc = fmaxf(mloc, ps[h][e]);
    for (int d = 32; d; d >>= 1) mloc = fmaxf(mloc, __shfl_xor(mloc, d));
    float mnew = fmaxf(m_run, mloc);
    // exp in place + denom
    float dloc = 0.f;
    for (int e = lane; e < ne; e += 64) {
      float p = __expf(ps[h][e] - mnew);
      ps[h][e] = p;
      dloc += p;
    }
    for (int d = 32; d; d >>= 1) dloc += __shfl_xor(dloc, d);
    float scale = __expf(m_run - mnew);
    d_run = d_run * scale + dloc;
    acc *= scale;
    // V accumulate, 4-way unrolled for memory ILP
    const size_t vb = 512 + (size_t)h * 64 + lane;
    int e = 0;
    for (; e + 4 <= ne; e += 4) {
      float v0 = (float)qkvz[(size_t)srcs[e]     * 1024 + vb];
      float v1 = (float)qkvz[(size_t)srcs[e + 1] * 1024 + vb];
      float v2 = (float)qkvz[(size_t)srcs[e + 2] * 1024 + vb];
      float v3 = (float)qkvz[(size_t)srcs[e + 3] * 1024 + vb];
      acc += ps[h][e] * v0 + ps[h][e + 1] * v1 + ps[h][e + 2] * v2 + ps[h][e + 3] * v3;
    }
    for (; e < ne; ++e)
      acc += ps[h][e] * (float)qkvz[(size_t)srcs[e] * 1024 + vb];
    m_run = mnew;
    __syncthreads();
  }
  float agg = acc / fmaxf(d_run, 1e-16f);
  float z = (float)qkvz[(size_t)node * 1024 + 768 + tid] + agg;
  // LayerNorm over 256
  float s = z;
  for (int d = 32; d; d >>= 1) s += __shfl_xor(s, d);
  __shared__ float w4[4], w4b[4];
  if (lane == 0) w4[h] = s;
  __syncthreads();
  float mu = (w4[0] + w4[1] + w4[2] + w4[3]) * (1.f / HID);
  float dv = z - mu;
  float qv = dv * dv;
  for (int d = 32; d; d >>= 1) qv += __shfl_xor(qv, d);
  if (lane == 0) w4b[h] = qv;
  __syncthreads();
  float var = (w4b[0] + w4b[1] + w4b[2] + w4b[3]) * (1.f / HID);
  float y = dv * (1.f / sqrtf(var + 1e-5f)) * g[tid] + b[tid];
  y = fmaxf(y, 0.f);
  h16[(size_t)node * HID + tid] = (_Float16)y;
}

// decode from fp16 h
__global__ void decode_kernel(const _Float16* __restrict__ h, const int* __restrict__ src,
                              const int* __restrict__ dst, float* __restrict__ out) {
  int wv = threadIdx.x >> 6, lane = threadIdx.x & 63;
  int p = blockIdx.x * 4 + wv;
  if (p >= NP) return;
  const f16x4* a = (const f16x4*)(h + (size_t)src[p] * HID);
  const f16x4* b = (const f16x4*)(h + (size_t)dst[p] * HID);
  f16x4 x = a[lane], y = b[lane];
  float s = (float)x[0] * (float)y[0] + (float)x[1] * (float)y[1] +
            (float)x[2] * (float)y[2] + (float)x[3] * (float)y[3];
  for (int d = 32; d; d >>= 1) s += __shfl_xor(s, d);
  if (lane == 0) out[p] = 1.f / (1.f + expf(-s));
}

// ---------------- host launch ----------------
extern "C" void kernel_launch(void* const* d_in, const int* in_sizes, int n_in,
                              void* d_out, int out_size, void* d_ws, size_t ws_size,
                              hipStream_t stream) {
  const float* x      = (const float*)d_in[0];
  const int*   ei     = (const int*)d_in[1];
  const int*   src    = (const int*)d_in[2];
  const int*   dst    = (const int*)d_in[3];
  const float* rwse_w = (const float*)d_in[4];
  const float* rwse_b = (const float*)d_in[5];
  const float* proj_w = (const float*)d_in[6];
  const float* proj_b = (const float*)d_in[7];
  const float* Wq     = (const float*)d_in[8];
  const float* bq     = (const float*)d_in[9];
  const float* Wk     = (const float*)d_in[10];
  const float* bk     = (const float*)d_in[11];
  const float* Wv     = (const float*)d_in[12];
  const float* bv     = (const float*)d_in[13];
  const float* Wsk    = (const float*)d_in[14];
  const float* bs     = (const float*)d_in[15];
  const float* ln_g   = (const float*)d_in[16];
  const float* ln_b   = (const float*)d_in[17];
  float* out = (float*)d_out;

  const size_t M8 = (size_t)NN * NN;    // 9,437,184 bytes per fp8 matrix
  char* base = (char*)d_ws;
  unsigned char* rw   = (unsigned char*)(base + 0 * M8);
  unsigned char* rwT  = (unsigned char*)(base + 1 * M8);
  unsigned char* rw2  = (unsigned char*)(base + 2 * M8);
  unsigned char* rw3  = (unsigned char*)(base + 3 * M8);
  unsigned char* rw4  = (unsigned char*)(base + 4 * M8);
  unsigned char* rw4T = (unsigned char*)(base + 5 * M8);
  unsigned char* rw8  = (unsigned char*)(base + 6 * M8);
  unsigned char* rw12 = (unsigned char*)(base + 7 * M8);
  unsigned char* rw2T = (unsigned char*)(base + 8 * M8);
  unsigned char* rw3T = (unsigned char*)(base + 9 * M8);
  float* adj = (float*)(base + 6 * M8);  // f32 [NN][NN] = slots 6..9; dead before rw8 written
  char* sm = base + 10 * M8;
  float* diags = (float*)sm; sm += (size_t)16 * NN * 4;
  int* cnt = (int*)sm; sm += 12288;
  int* cur = (int*)sm; sm += 12288;
  int* off = (int*)sm; sm += 16384;
  int* csrc = (int*)sm; sm += (size_t)NE * 4;
  _Float16* qkvz16 = (_Float16*)sm; sm += (size_t)NN * 1024 * 2;
  _Float16* h16  = (_Float16*)sm; sm += (size_t)NN * HID * 2;
  _Float16* xc16 = (_Float16*)sm; sm += (size_t)NN * KPAD * 2;
  _Float16* wt_proj = (_Float16*)sm; sm += (size_t)HID * KPAD * 2;
  _Float16* wt_cat[2]; float* bcat[2];
  for (int l = 0; l < 2; ++l) {
    wt_cat[l] = (_Float16*)sm; sm += (size_t)4 * HID * HID * 2;
    bcat[l]   = (float*)sm;    sm += 1024 * 4;
  }
  (void)in_sizes; (void)n_in; (void)out_size; (void)ws_size;

  const dim3 B256(256);
  const dim3 gT3(NN / 64, NN / 64, 3);
  const int  gG = (NN / 128) * (NN / 128);     // 576
  const dim3 gW(1024 / 64, NN / 64);
  const dim3 gS(HID / 64, NN / 64);

  // --- zero adj + counters ---
  hipMemsetAsync(adj, 0, (size_t)NN * NN * 4, stream);
  hipMemsetAsync(cnt, 0, 24576, stream);   // cnt + cur contiguous

  // K1: edges | wconv proj | wconv cat0 | wconv cat1   (576+160+1024+1024 blocks)
  prep_kernel<<<2784, B256, 0, stream>>>(ei, adj, cnt, proj_w, wt_proj,
                                         Wq, Wk, Wv, Wsk, bq, bk, bv, bs,
                                         wt_cat[0], wt_cat[1], bcat[0], bcat[1]);
  // K2: rownorm | csr_scan
  rownorm_scan_kernel<<<NN + 1, B256, 0, stream>>>(adj, rw, diags, cnt, off);
  // K3: csr_fill | transpose rw->rwT
  fill_transpose_kernel<<<576 + 2304, B256, 0, stream>>>(ei, ei + NE, off, cur, csrc, rw, rwT);

  // --- RWSE power chain (fp8, uniformly scaled by FP8_S) ---
  gemm_fp8_nt<<<gG, B256, 0, stream>>>(rw, rwT, rw2, NN);    // rw2 = rw*rw
  gemm_fp8_nt<<<gG, B256, 0, stream>>>(rw2, rwT, rw3, NN);   // rw3 = rw2*rw
  gemm_fp8_nt<<<gG, B256, 0, stream>>>(rw3, rwT, rw4, NN);   // rw4 = rw3*rw
  transpose3_kernel<<<gT3, B256, 0, stream>>>(rw4, rw4T, rw2, rw2T, rw3, rw3T);
  gemm_fp8_nt<<<gG, B256, 0, stream>>>(rw4, rw4T, rw8, NN);  // rw8 = rw4*rw4
  gemm_fp8_nt<<<gG, B256, 0, stream>>>(rw8, rw4T, rw12, NN); // rw12 = rw8*rw4
  diag_all_kernel<<<NN, B256, 0, stream>>>(rw, rw2, rw4, rw8, rw12,
                                           rwT, rw2T, rw3T, rw4T, diags);

  // --- input projection (PE inline in concat) ---
  concat16_kernel<<<(NN * KPAD + 255) / 256, B256, 0, stream>>>(x, diags, rwse_w, rwse_b, xc16);
  gemm_f16_node<<<gS, B256, 0, stream>>>(xc16, wt_proj, proj_b, nullptr, h16, NN, HID, KPAD);

  // --- transformer layers ---
  for (int l = 0; l < 2; ++l) {
    gemm_f16_node<<<gW, B256, 0, stream>>>(h16, wt_cat[l], bcat[l], h16, qkvz16,
                                           NN, 1024, HID);
    attn_ln_kernel<<<NN, B256, 0, stream>>>(off, csrc, qkvz16, ln_g + l * HID, ln_b + l * HID,
                                            h16);
  }

  decode_kernel<<<NP / 4, B256, 0, stream>>>(h16, src, dst, out);
}